// Round 2
// baseline (699.233 us; speedup 1.0000x reference)
//
#include <hip/hip_runtime.h>

// ---------------------------------------------------------------------------
// OHEM cross-entropy, 5 kernels, zero global atomics:
//   1) loss_k: loss[i] = log(sum exp(pred[i,:])) - pred[i,target[i]].
//      Pure streaming (no LDS, no reg cap): 2048 blocks x 256 thr,
//      16-lane group per row, quad-row float4 loads, wave shuffles only.
//   2) hist_k: bin loss[] (linear, [0,16), width 1/256) into per-block LDS
//      histograms (u32 cnt + f32 sum), flushed to a private slab. 512 slabs.
//   3) reduce1_k: 256 blocks (16 bin-chunks x 16 slab-chunks) -> 16 partials.
//   4) reduce2_k: fold 16 partials -> cnt[4096], dsum[4096].
//   5) scan_k: suffix-scan from the top, pivot bin, mean of top k via
//      exact sums above pivot + r * (pivot bin average).
// ---------------------------------------------------------------------------

#define NB 4096
#define G  512
#define CH 16            // slab chunks in reduce1
#define SPC (G / CH)     // 32 slabs per chunk
#define SCALE 256.0f

__global__ __launch_bounds__(256) void loss_k(const float* __restrict__ pred,
                                              const int* __restrict__ target,
                                              float* __restrict__ loss,
                                              int N) {
    int t    = threadIdx.x;
    int gtid = blockIdx.x * 256 + t;
    int wave = gtid >> 6;
    int lane = t & 63;
    int g4   = lane >> 4;              // which row of the quad (16 lanes per row)
    int l16  = lane & 15;
    int nw   = (gridDim.x * 256) >> 6; // total waves

    for (int r = wave * 8; r < N; r += nw * 8) {
        // clamp rows so all lanes stay active for shuffles; commit is guarded
        int rowA = r + g4;       if (rowA > N - 1) rowA = N - 1;
        int rowB = r + 4 + g4;   if (rowB > N - 1) rowB = N - 1;
        const float4* pa = (const float4*)(pred + (size_t)rowA * 128);
        const float4* pb = (const float4*)(pred + (size_t)rowB * 128);
        float4 a1 = pa[l16], a2 = pa[l16 + 16];   // cols l16*4..+3, 64+l16*4..+3
        float4 b1 = pb[l16], b2 = pb[l16 + 16];
        int ta = target[rowA], tb = target[rowB];

        float ea = __expf(a1.x) + __expf(a1.y) + __expf(a1.z) + __expf(a1.w)
                 + __expf(a2.x) + __expf(a2.y) + __expf(a2.z) + __expf(a2.w);
        float eb = __expf(b1.x) + __expf(b1.y) + __expf(b1.z) + __expf(b1.w)
                 + __expf(b2.x) + __expf(b2.y) + __expf(b2.z) + __expf(b2.w);
        #pragma unroll
        for (int off = 1; off < 16; off <<= 1) {
            ea += __shfl_xor(ea, off);
            eb += __shfl_xor(eb, off);
        }
        // fetch pred[row, target[row]]: owner lane (ta>>2)&15 in this 16-group
        float4 sa = (ta & 64) ? a2 : a1;
        float xsa = (ta & 2) ? ((ta & 1) ? sa.w : sa.z)
                             : ((ta & 1) ? sa.y : sa.x);
        float xta = __shfl(xsa, (lane & 48) + ((ta >> 2) & 15));
        float4 sb = (tb & 64) ? b2 : b1;
        float xsb = (tb & 2) ? ((tb & 1) ? sb.w : sb.z)
                             : ((tb & 1) ? sb.y : sb.x);
        float xtb = __shfl(xsb, (lane & 48) + ((tb >> 2) & 15));

        if (l16 == 0) {
            float la = fmaxf(__logf(ea) - xta, 0.0f);
            float lb = fmaxf(__logf(eb) - xtb, 0.0f);
            if (r + g4 < N)     loss[r + g4]     = la;
            if (r + 4 + g4 < N) loss[r + 4 + g4] = lb;
        }
    }
}

__global__ __launch_bounds__(256) void hist_k(const float* __restrict__ loss,
                                              unsigned* __restrict__ priv_cnt,
                                              float* __restrict__ priv_sum,
                                              int N) {
    __shared__ unsigned hc[NB];
    __shared__ float    hs[NB];
    int t = threadIdx.x;
    for (int i = t; i < NB; i += 256) { hc[i] = 0u; hs[i] = 0.0f; }
    __syncthreads();

    int nv = N >> 2;
    const float4* l4 = (const float4*)loss;
    int stride = gridDim.x * 256;
    for (int i = blockIdx.x * 256 + t; i < nv; i += stride) {
        float4 v = l4[i];
        int b0 = min((int)(v.x * SCALE), NB - 1);
        atomicAdd(&hc[b0], 1u); atomicAdd(&hs[b0], v.x);
        int b1 = min((int)(v.y * SCALE), NB - 1);
        atomicAdd(&hc[b1], 1u); atomicAdd(&hs[b1], v.y);
        int b2 = min((int)(v.z * SCALE), NB - 1);
        atomicAdd(&hc[b2], 1u); atomicAdd(&hs[b2], v.z);
        int b3 = min((int)(v.w * SCALE), NB - 1);
        atomicAdd(&hc[b3], 1u); atomicAdd(&hs[b3], v.w);
    }
    for (int i = (nv << 2) + blockIdx.x * 256 + t; i < N; i += stride) {
        float v = loss[i];
        int b = min((int)(v * SCALE), NB - 1);
        atomicAdd(&hc[b], 1u); atomicAdd(&hs[b], v);
    }
    __syncthreads();
    unsigned base = blockIdx.x * NB;
    for (int i = t; i < NB; i += 256) {
        priv_cnt[base + i] = hc[i];
        priv_sum[base + i] = hs[i];
    }
}

__global__ __launch_bounds__(256) void reduce1_k(const unsigned* __restrict__ priv_cnt,
                                                 const float* __restrict__ priv_sum,
                                                 unsigned* __restrict__ pcnt,
                                                 double* __restrict__ psum) {
    int bc = blockIdx.x & 15;           // 16 bin chunks x 256 bins
    int sc = blockIdx.x >> 4;           // CH slab chunks x SPC slabs
    int bin = bc * 256 + threadIdx.x;
    int g0 = sc * SPC;
    unsigned c = 0;
    double s = 0.0;
    #pragma unroll 4
    for (int g = g0; g < g0 + SPC; g++) {
        c += priv_cnt[(size_t)g * NB + bin];
        s += (double)priv_sum[(size_t)g * NB + bin];
    }
    pcnt[(size_t)sc * NB + bin] = c;
    psum[(size_t)sc * NB + bin] = s;
}

__global__ __launch_bounds__(256) void reduce2_k(const unsigned* __restrict__ pcnt,
                                                 const double* __restrict__ psum,
                                                 unsigned* __restrict__ cnt,
                                                 double* __restrict__ dsum) {
    int bin = blockIdx.x * 256 + threadIdx.x;   // 16 blocks x 256 = 4096 bins
    unsigned c = 0;
    double s = 0.0;
    #pragma unroll
    for (int k = 0; k < CH; k++) {
        c += pcnt[(size_t)k * NB + bin];
        s += psum[(size_t)k * NB + bin];
    }
    cnt[bin] = c;
    dsum[bin] = s;
}

__global__ __launch_bounds__(256) void scan_k(const unsigned* __restrict__ cnt,
                                              const double* __restrict__ dsum,
                                              float* __restrict__ out, int K) {
    __shared__ unsigned sc[256];
    __shared__ double   ss[256];
    __shared__ int      pivot;
    __shared__ unsigned above_c;
    __shared__ double   above_s;
    int t = threadIdx.x;
    unsigned c = 0;
    double s = 0.0;
    #pragma unroll
    for (int j = 0; j < 16; j++) { c += cnt[t * 16 + j]; s += dsum[t * 16 + j]; }
    sc[t] = c;
    ss[t] = s;
    __syncthreads();
    #pragma unroll
    for (int step = 1; step < 256; step <<= 1) {
        unsigned vc = (t + step < 256) ? sc[t + step] : 0u;
        double   vs = (t + step < 256) ? ss[t + step] : 0.0;
        __syncthreads();
        sc[t] += vc;
        ss[t] += vs;
        __syncthreads();
    }
    unsigned incl = sc[t];
    unsigned abv  = (t < 255) ? sc[t + 1] : 0u;
    if (incl >= (unsigned)K && abv < (unsigned)K) {
        pivot   = t;
        above_c = abv;
        above_s = (t < 255) ? ss[t + 1] : 0.0;
    }
    __syncthreads();
    if (t == 0) {
        int pc = pivot;
        unsigned acc = above_c;
        double  accs = above_s;
        for (int b = 15; b >= 0; b--) {
            unsigned cb = cnt[pc * 16 + b];
            if (acc + cb >= (unsigned)K) {
                unsigned rIn = (unsigned)K - acc;
                double   avg = dsum[pc * 16 + b] / (double)cb;
                out[0] = (float)((accs + (double)rIn * avg) / (double)K);
                return;
            }
            acc  += cb;
            accs += dsum[pc * 16 + b];
        }
    }
}

extern "C" void kernel_launch(void* const* d_in, const int* in_sizes, int n_in,
                              void* d_out, int out_size, void* d_ws, size_t ws_size,
                              hipStream_t stream) {
    const float* pred   = (const float*)d_in[0];
    const int*   target = (const int*)d_in[1];
    int N = in_sizes[1];                    // pred is [N,128]
    int K = (int)((double)N * 0.7);         // matches python int(N*0.7)

    char* ws = (char*)d_ws;
    unsigned* priv_cnt = (unsigned*)ws;  ws += (size_t)G * NB * 4;   // 8 MB
    float*    priv_sum = (float*)ws;     ws += (size_t)G * NB * 4;   // 8 MB
    unsigned* pcnt     = (unsigned*)ws;  ws += (size_t)CH * NB * 4;  // 256 KB
    double*   psum     = (double*)ws;    ws += (size_t)CH * NB * 8;  // 512 KB
    unsigned* cnt      = (unsigned*)ws;  ws += (size_t)NB * 4;       // 16 KB
    double*   dsum     = (double*)ws;    ws += (size_t)NB * 8;       // 32 KB
    float*    loss     = (float*)ws;                                 // 4 MB

    loss_k<<<2048, 256, 0, stream>>>(pred, target, loss, N);
    hist_k<<<G, 256, 0, stream>>>(loss, priv_cnt, priv_sum, N);
    reduce1_k<<<CH * 16, 256, 0, stream>>>(priv_cnt, priv_sum, pcnt, psum);
    reduce2_k<<<NB / 256, 256, 0, stream>>>(pcnt, psum, cnt, dsum);
    scan_k<<<1, 256, 0, stream>>>(cnt, dsum, (float*)d_out, K);
}

// Round 3
// 695.400 us; speedup vs baseline: 1.0055x; 1.0055x over previous
//
#include <hip/hip_runtime.h>

// ---------------------------------------------------------------------------
// OHEM cross-entropy, 5 kernels, zero global atomics:
//   1) loss_k: loss[i] = log(sum exp(pred[i,:])) - pred[i,target[i]].
//      32 lanes per row (one float4/lane = one fully-contiguous 1KB segment
//      per wave load instruction), 8 rows per wave-iteration, explicit
//      register double-buffering (next iter's loads issued before current
//      iter's exp/shuffle chain). 2048 blocks x 256 thr.
//   2) hist_k: bin loss[] (linear, [0,16), width 1/256) into per-block LDS
//      histograms (u32 cnt + f32 sum), flushed to a private slab. 512 slabs.
//   3) reduce1_k: 256 blocks (16 bin-chunks x 16 slab-chunks) -> 16 partials.
//   4) reduce2_k: fold 16 partials -> cnt[4096], dsum[4096].
//   5) scan_k: suffix-scan from the top, pivot bin, mean of top k via
//      exact sums above pivot + r * (pivot bin average).
// ---------------------------------------------------------------------------

#define NB 4096
#define G  512
#define CH 16            // slab chunks in reduce1
#define SPC (G / CH)     // 32 slabs per chunk
#define SCALE 256.0f

#define E4(v)   (__expf((v).x) + __expf((v).y) + __expf((v).z) + __expf((v).w))
#define SEL4(v, t) (((t) & 2) ? (((t) & 1) ? (v).w : (v).z) \
                              : (((t) & 1) ? (v).y : (v).x))

// Load 8 rows starting at r: lane covers float4 (l32) of row r + 2*j + half.
// Each instruction's 64 lanes touch one contiguous aligned 1KB block (2 rows).
#define LOADQ(r, v0, v1, v2, v3, tt) do {                                   \
    int _r0 = (r) + half;     if (_r0 > N - 1) _r0 = N - 1;                 \
    int _r1 = (r) + 2 + half; if (_r1 > N - 1) _r1 = N - 1;                 \
    int _r2 = (r) + 4 + half; if (_r2 > N - 1) _r2 = N - 1;                 \
    int _r3 = (r) + 6 + half; if (_r3 > N - 1) _r3 = N - 1;                 \
    v0 = p4[(size_t)_r0 * 32 + l32];                                        \
    v1 = p4[(size_t)_r1 * 32 + l32];                                        \
    v2 = p4[(size_t)_r2 * 32 + l32];                                        \
    v3 = p4[(size_t)_r3 * 32 + l32];                                        \
    int _rt = (r) + 2 * (l32 & 3) + half; if (_rt > N - 1) _rt = N - 1;     \
    tt = target[_rt];                                                       \
} while (0)

#define COMPUTEQ(r, v0, v1, v2, v3, tt) do {                                \
    float s0 = E4(v0), s1 = E4(v1), s2 = E4(v2), s3 = E4(v3);               \
    _Pragma("unroll")                                                       \
    for (int off = 1; off < 32; off <<= 1) {                                \
        s0 += __shfl_xor(s0, off);                                          \
        s1 += __shfl_xor(s1, off);                                          \
        s2 += __shfl_xor(s2, off);                                          \
        s3 += __shfl_xor(s3, off);                                          \
    }                                                                       \
    int hb = half << 5;                                                     \
    int t0 = __shfl(tt, hb + 0), t1 = __shfl(tt, hb + 1);                   \
    int t2 = __shfl(tt, hb + 2), t3 = __shfl(tt, hb + 3);                   \
    float xt0 = __shfl(SEL4(v0, t0), hb + (t0 >> 2));                       \
    float xt1 = __shfl(SEL4(v1, t1), hb + (t1 >> 2));                       \
    float xt2 = __shfl(SEL4(v2, t2), hb + (t2 >> 2));                       \
    float xt3 = __shfl(SEL4(v3, t3), hb + (t3 >> 2));                       \
    if (l32 < 4) {                                                          \
        int row  = (r) + 2 * l32 + half;                                    \
        float s  = l32 == 0 ? s0  : l32 == 1 ? s1  : l32 == 2 ? s2  : s3;   \
        float xt = l32 == 0 ? xt0 : l32 == 1 ? xt1 : l32 == 2 ? xt2 : xt3;  \
        if (row < N) loss[row] = fmaxf(__logf(s) - xt, 0.0f);               \
    }                                                                       \
} while (0)

__global__ __launch_bounds__(256) void loss_k(const float* __restrict__ pred,
                                              const int* __restrict__ target,
                                              float* __restrict__ loss,
                                              int N) {
    int t    = threadIdx.x;
    int gtid = blockIdx.x * 256 + t;
    int wave = gtid >> 6;
    int lane = t & 63;
    int half = lane >> 5;              // which of the 2 rows per load instr
    int l32  = lane & 31;              // float4 index within the row
    int nw   = (gridDim.x * 256) >> 6;
    int step = nw * 8;
    const float4* p4 = (const float4*)pred;

    int r = wave * 8;
    if (r >= N) return;

    float4 a0, a1, a2, a3, b0, b1, b2, b3;
    int ta, tb;
    LOADQ(r, a0, a1, a2, a3, ta);
    while (r + step < N) {
        LOADQ(r + step, b0, b1, b2, b3, tb);
        COMPUTEQ(r, a0, a1, a2, a3, ta);
        r += step;
        if (r + step < N) {
            LOADQ(r + step, a0, a1, a2, a3, ta);
            COMPUTEQ(r, b0, b1, b2, b3, tb);
            r += step;
        } else {
            COMPUTEQ(r, b0, b1, b2, b3, tb);
            return;
        }
    }
    COMPUTEQ(r, a0, a1, a2, a3, ta);
}

__global__ __launch_bounds__(256) void hist_k(const float* __restrict__ loss,
                                              unsigned* __restrict__ priv_cnt,
                                              float* __restrict__ priv_sum,
                                              int N) {
    __shared__ unsigned hc[NB];
    __shared__ float    hs[NB];
    int t = threadIdx.x;
    for (int i = t; i < NB; i += 256) { hc[i] = 0u; hs[i] = 0.0f; }
    __syncthreads();

    int nv = N >> 2;
    const float4* l4 = (const float4*)loss;
    int stride = gridDim.x * 256;
    for (int i = blockIdx.x * 256 + t; i < nv; i += stride) {
        float4 v = l4[i];
        int b0 = min((int)(v.x * SCALE), NB - 1);
        atomicAdd(&hc[b0], 1u); atomicAdd(&hs[b0], v.x);
        int b1 = min((int)(v.y * SCALE), NB - 1);
        atomicAdd(&hc[b1], 1u); atomicAdd(&hs[b1], v.y);
        int b2 = min((int)(v.z * SCALE), NB - 1);
        atomicAdd(&hc[b2], 1u); atomicAdd(&hs[b2], v.z);
        int b3 = min((int)(v.w * SCALE), NB - 1);
        atomicAdd(&hc[b3], 1u); atomicAdd(&hs[b3], v.w);
    }
    for (int i = (nv << 2) + blockIdx.x * 256 + t; i < N; i += stride) {
        float v = loss[i];
        int b = min((int)(v * SCALE), NB - 1);
        atomicAdd(&hc[b], 1u); atomicAdd(&hs[b], v);
    }
    __syncthreads();
    unsigned base = blockIdx.x * NB;
    for (int i = t; i < NB; i += 256) {
        priv_cnt[base + i] = hc[i];
        priv_sum[base + i] = hs[i];
    }
}

__global__ __launch_bounds__(256) void reduce1_k(const unsigned* __restrict__ priv_cnt,
                                                 const float* __restrict__ priv_sum,
                                                 unsigned* __restrict__ pcnt,
                                                 double* __restrict__ psum) {
    int bc = blockIdx.x & 15;           // 16 bin chunks x 256 bins
    int sc = blockIdx.x >> 4;           // CH slab chunks x SPC slabs
    int bin = bc * 256 + threadIdx.x;
    int g0 = sc * SPC;
    unsigned c = 0;
    double s = 0.0;
    #pragma unroll 4
    for (int g = g0; g < g0 + SPC; g++) {
        c += priv_cnt[(size_t)g * NB + bin];
        s += (double)priv_sum[(size_t)g * NB + bin];
    }
    pcnt[(size_t)sc * NB + bin] = c;
    psum[(size_t)sc * NB + bin] = s;
}

__global__ __launch_bounds__(256) void reduce2_k(const unsigned* __restrict__ pcnt,
                                                 const double* __restrict__ psum,
                                                 unsigned* __restrict__ cnt,
                                                 double* __restrict__ dsum) {
    int bin = blockIdx.x * 256 + threadIdx.x;   // 16 blocks x 256 = 4096 bins
    unsigned c = 0;
    double s = 0.0;
    #pragma unroll
    for (int k = 0; k < CH; k++) {
        c += pcnt[(size_t)k * NB + bin];
        s += psum[(size_t)k * NB + bin];
    }
    cnt[bin] = c;
    dsum[bin] = s;
}

__global__ __launch_bounds__(256) void scan_k(const unsigned* __restrict__ cnt,
                                              const double* __restrict__ dsum,
                                              float* __restrict__ out, int K) {
    __shared__ unsigned sc[256];
    __shared__ double   ss[256];
    __shared__ int      pivot;
    __shared__ unsigned above_c;
    __shared__ double   above_s;
    int t = threadIdx.x;
    unsigned c = 0;
    double s = 0.0;
    #pragma unroll
    for (int j = 0; j < 16; j++) { c += cnt[t * 16 + j]; s += dsum[t * 16 + j]; }
    sc[t] = c;
    ss[t] = s;
    __syncthreads();
    #pragma unroll
    for (int step = 1; step < 256; step <<= 1) {
        unsigned vc = (t + step < 256) ? sc[t + step] : 0u;
        double   vs = (t + step < 256) ? ss[t + step] : 0.0;
        __syncthreads();
        sc[t] += vc;
        ss[t] += vs;
        __syncthreads();
    }
    unsigned incl = sc[t];
    unsigned abv  = (t < 255) ? sc[t + 1] : 0u;
    if (incl >= (unsigned)K && abv < (unsigned)K) {
        pivot   = t;
        above_c = abv;
        above_s = (t < 255) ? ss[t + 1] : 0.0;
    }
    __syncthreads();
    if (t == 0) {
        int pc = pivot;
        unsigned acc = above_c;
        double  accs = above_s;
        for (int b = 15; b >= 0; b--) {
            unsigned cb = cnt[pc * 16 + b];
            if (acc + cb >= (unsigned)K) {
                unsigned rIn = (unsigned)K - acc;
                double   avg = dsum[pc * 16 + b] / (double)cb;
                out[0] = (float)((accs + (double)rIn * avg) / (double)K);
                return;
            }
            acc  += cb;
            accs += dsum[pc * 16 + b];
        }
    }
}

extern "C" void kernel_launch(void* const* d_in, const int* in_sizes, int n_in,
                              void* d_out, int out_size, void* d_ws, size_t ws_size,
                              hipStream_t stream) {
    const float* pred   = (const float*)d_in[0];
    const int*   target = (const int*)d_in[1];
    int N = in_sizes[1];                    // pred is [N,128]
    int K = (int)((double)N * 0.7);         // matches python int(N*0.7)

    char* ws = (char*)d_ws;
    unsigned* priv_cnt = (unsigned*)ws;  ws += (size_t)G * NB * 4;   // 8 MB
    float*    priv_sum = (float*)ws;     ws += (size_t)G * NB * 4;   // 8 MB
    unsigned* pcnt     = (unsigned*)ws;  ws += (size_t)CH * NB * 4;  // 256 KB
    double*   psum     = (double*)ws;    ws += (size_t)CH * NB * 8;  // 512 KB
    unsigned* cnt      = (unsigned*)ws;  ws += (size_t)NB * 4;       // 16 KB
    double*   dsum     = (double*)ws;    ws += (size_t)NB * 8;       // 32 KB
    float*    loss     = (float*)ws;                                 // 4 MB

    loss_k<<<2048, 256, 0, stream>>>(pred, target, loss, N);
    hist_k<<<G, 256, 0, stream>>>(loss, priv_cnt, priv_sum, N);
    reduce1_k<<<CH * 16, 256, 0, stream>>>(priv_cnt, priv_sum, pcnt, psum);
    reduce2_k<<<NB / 256, 256, 0, stream>>>(pcnt, psum, cnt, dsum);
    scan_k<<<1, 256, 0, stream>>>(cnt, dsum, (float*)d_out, K);
}